// Round 12
// baseline (147.893 us; speedup 1.0000x reference)
//
#include <hip/hip_runtime.h>
#include <cstdint>
#include <cstddef>

// CPDLoss (SSD MultiBox-style): B=8, A=131072, M=64.
// R12: exact spatial filtering. Anchors counting-sorted by 8x8 cell (3 tiny
// kernels); k_match blocks own spatially-compact anchor runs, compute their
// bbox (DPP min/max), and compact only INTERSECTING truths (~8-14 of 32).
// Omitted pairs have inter=0 -> q=0 -> provably no effect on either argmax
// (per-anchor init bv=0/bm=firstValidM; per-truth q=0 seed via sortPos0).
// memset -> sort1/2/3 -> k_match (match+losses+h1+ceBits, sorted order) ->
// k_fix (recompute+patch <=512 forced anchors) -> k_sel2 -> k_final.

#define A_N 131072
#define B_N 8
#define M_N 64
#define OVTH 0.5f
#define VAR0 0.1f
#define CNT_SH 46
#define SUM_MASK ((1ull << CNT_SH) - 1ull)
#define FIXF 1048576.0f
#define INV_FIX (1.0 / 1048576.0)
// ws u64-word map:
// 0 lossL | 1 lossCp | 2..5 numpos[8]u32 | 6 lossCn | 7 ticket
// 8..39 cellCnt[64]u32 | 40..71 cursor[64]u32 | 72 sortPos0
// 80 bpi[512] | 592 h1[8*2048] | 16976 h2[8*2048] | end 33360
#define W_CNT 8
#define W_CUR 40
#define W_SP0 72
#define W_BPI 80
#define W_H1  592
#define W_H2  16976
#define ZWORDS 33360
#define ZBYTES (ZWORDS * 8)

static __device__ __forceinline__ unsigned long long packCE(float ce) {
  return (1ull << CNT_SH) | (unsigned long long)(ce * FIXF + 0.5f);
}
static __device__ __forceinline__ float sl1(float d) {
  return d < 1.f ? 0.5f * d * d : d - 0.5f;
}
// DPP folds with old=src (bound_ctrl=false): invalid lanes keep own value --
// safe for both min and max. CTRL immediate via template.
template <int CTRL>
static __device__ __forceinline__ float dppMax(float v) {
  int o = __builtin_amdgcn_update_dpp(__float_as_int(v), __float_as_int(v),
                                      CTRL, 0xf, 0xf, false);
  return fmaxf(v, __int_as_float(o));
}
template <int CTRL>
static __device__ __forceinline__ float dppMin(float v) {
  int o = __builtin_amdgcn_update_dpp(__float_as_int(v), __float_as_int(v),
                                      CTRL, 0xf, 0xf, false);
  return fminf(v, __int_as_float(o));
}
static __device__ __forceinline__ float waveMax(float v) {
  v = dppMax<0x111>(v); v = dppMax<0x112>(v); v = dppMax<0x114>(v);
  v = dppMax<0x118>(v); v = dppMax<0x142>(v); v = dppMax<0x143>(v);
  return __int_as_float(__builtin_amdgcn_readlane(__float_as_int(v), 63));
}
static __device__ __forceinline__ float waveMin(float v) {
  v = dppMin<0x111>(v); v = dppMin<0x112>(v); v = dppMin<0x114>(v);
  v = dppMin<0x118>(v); v = dppMin<0x142>(v); v = dppMin<0x143>(v);
  return __int_as_float(__builtin_amdgcn_readlane(__float_as_int(v), 63));
}

// ------------------------------------------------------------- sort: count
__global__ void k_sort1(const float4* __restrict__ anchors,
                        unsigned long long* __restrict__ ws64)
{
  unsigned int* cellCnt = (unsigned int*)(ws64 + W_CNT);
  __shared__ unsigned int c[64];
  const int tid = threadIdx.x;
  if (tid < 64) c[tid] = 0u;
  __syncthreads();
  int gid = blockIdx.x * 256 + tid;
  float4 an = anchors[gid];
  int cell = min((int)(an.y * 8.f), 7) * 8 + min((int)(an.x * 8.f), 7);
  atomicAdd(&c[cell], 1u);
  __syncthreads();
  if (tid < 64 && c[tid]) atomicAdd(&cellCnt[tid], c[tid]);
}

// -------------------------------------------------------------- sort: scan
__global__ void k_sort2(unsigned long long* __restrict__ ws64)
{
  unsigned int* cellCnt = (unsigned int*)(ws64 + W_CNT);
  unsigned int* cursor  = (unsigned int*)(ws64 + W_CUR);
  if (threadIdx.x == 0) {
    unsigned int s = 0;
    for (int i = 0; i < 64; ++i) { cursor[i] = s; s += cellCnt[i]; }
  }
}

// ----------------------------------------------------------- sort: scatter
__global__ void k_sort3(const float4* __restrict__ anchors,
                        unsigned long long* __restrict__ ws64,
                        float4* __restrict__ sortedA,
                        unsigned int* __restrict__ sortedId)
{
  unsigned int* cursor  = (unsigned int*)(ws64 + W_CUR);
  unsigned int* sortPos0 = (unsigned int*)(ws64 + W_SP0);
  __shared__ unsigned int bcnt[64];
  __shared__ unsigned int bbase[64];
  const int tid = threadIdx.x;
  if (tid < 64) bcnt[tid] = 0u;
  __syncthreads();
  int gid = blockIdx.x * 256 + tid;
  float4 an = anchors[gid];
  int cell = min((int)(an.y * 8.f), 7) * 8 + min((int)(an.x * 8.f), 7);
  unsigned int my = atomicAdd(&bcnt[cell], 1u);
  __syncthreads();
  if (tid < 64) bbase[tid] = bcnt[tid] ? atomicAdd(&cursor[tid], bcnt[tid]) : 0u;
  __syncthreads();
  unsigned int pos = bbase[cell] + my;
  sortedA[pos] = an;
  sortedId[pos] = (unsigned int)gid;
  if (gid == 0) *sortPos0 = pos;
}

// ---------------------------------------------------------------- match+loss
// 512 thr/block, 4 anchors/thread (sorted positions, stride 512), grid (64,8).
// bbox of block's anchors (DPP min/max) -> compact intersecting valid truths.
// Per candidate truth: 4 IoU (rcp), per-anchor strict-> (np first-max over the
// implicit-zero row), DPP wave-max + ballot lowest-lane tie -> per-wave key
// (q_bits<<32 | 0x7FFFFFFF - sortedPos). Phase C: losses sans override;
// negatives -> ceBits[sortedPos] + h1. conf/loc preds gathered at original id.
__launch_bounds__(512, 4)
__global__ void k_match(const float4* __restrict__ sortedA,
                        const unsigned int* __restrict__ sortedId,
                        const float*  __restrict__ targets,
                        const float2* __restrict__ loc_pred,
                        const float2* __restrict__ conf_pred,
                        unsigned long long* __restrict__ ws64,
                        unsigned int* __restrict__ ceBits)
{
  double* lossL  = (double*)(ws64 + 0);
  double* lossCp = (double*)(ws64 + 1);
  unsigned int* numpos = (unsigned int*)(ws64 + 2);
  unsigned long long* bpi = ws64 + W_BPI;
  unsigned long long* h1  = ws64 + W_H1;

  __shared__ float4 sTB[M_N];
  __shared__ float4 sCBX[M_N];
  __shared__ float  sCBA[M_N];
  __shared__ int    sCBM[M_N];
  __shared__ int    sNC; __shared__ int sNV; __shared__ int sFV;
  __shared__ float  sRed[8][4];
  __shared__ float  sBB[4];
  __shared__ unsigned long long sKey[M_N][8];
  __shared__ unsigned long long hh[2048];
  __shared__ double rL[8], rC[8];
  __shared__ unsigned int rN[8];

  const int tid = threadIdx.x;
  const int wave = tid >> 6, lane = tid & 63;
  const int b = blockIdx.y;
  const int base = blockIdx.x * 2048;

  sKey[tid >> 3][tid & 7] = 0ull;
  for (int j = tid; j < 2048; j += 512) hh[j] = 0ull;

  // load anchors (sorted order) + per-thread bbox
  float ax1[4], ay1[4], ax2[4], ay2[4], sa[4];
  int aId[4];
  float bx1 = 1e30f, by1 = 1e30f, bx2 = -1e30f, by2 = -1e30f;
  #pragma unroll
  for (int i = 0; i < 4; ++i) {
    const int p = base + tid + i * 512;
    float4 an = sortedA[p];
    aId[i] = (int)sortedId[p];
    ax1[i] = an.x - an.z * 0.5f; ay1[i] = an.y - an.w * 0.5f;
    ax2[i] = an.x + an.z * 0.5f; ay2[i] = an.y + an.w * 0.5f;
    sa[i] = (ax2[i] - ax1[i]) * (ay2[i] - ay1[i]);
    bx1 = fminf(bx1, ax1[i]); by1 = fminf(by1, ay1[i]);
    bx2 = fmaxf(bx2, ax2[i]); by2 = fmaxf(by2, ay2[i]);
  }
  bx1 = waveMin(bx1); by1 = waveMin(by1);
  bx2 = waveMax(bx2); by2 = waveMax(by2);
  if (lane == 0) { sRed[wave][0] = bx1; sRed[wave][1] = by1;
                   sRed[wave][2] = bx2; sRed[wave][3] = by2; }
  __syncthreads();
  if (tid == 0) {
    float a0 = 1e30f, a1 = 1e30f, a2 = -1e30f, a3 = -1e30f;
    #pragma unroll
    for (int w = 0; w < 8; ++w) {
      a0 = fminf(a0, sRed[w][0]); a1 = fminf(a1, sRed[w][1]);
      a2 = fmaxf(a2, sRed[w][2]); a3 = fmaxf(a3, sRed[w][3]);
    }
    sBB[0] = a0; sBB[1] = a1; sBB[2] = a2; sBB[3] = a3;
  }
  __syncthreads();

  // prep: load targets, validity, candidate test vs block bbox, compact
  if (tid < M_N) {
    const float* t = targets + ((size_t)b * M_N + tid) * 5;
    float x1 = t[0], y1 = t[1], x2 = t[2], y2 = t[3], lab = t[4];
    sTB[tid] = make_float4(x1, y1, x2, y2);
    bool valid = lab > 0.f;
    unsigned long long vm = __ballot(valid);
    bool cand = valid && (x1 <= sBB[2]) && (x2 >= sBB[0]) &&
                         (y1 <= sBB[3]) && (y2 >= sBB[1]);
    unsigned long long cm = __ballot(cand);
    int cp = __popcll(cm & ((1ull << tid) - 1ull));
    if (cand) {
      sCBX[cp] = make_float4(x1, y1, x2, y2);
      sCBA[cp] = (x2 - x1) * (y2 - y1);
      sCBM[cp] = tid;
    }
    if (tid == 0) {
      sNC = (int)__popcll(cm);
      sNV = (int)__popcll(vm);
      sFV = vm ? (__ffsll(vm) - 1) : 0;
    }
  }
  __syncthreads();

  const int nc = sNC;
  float bv[4]; int bm[4];
  {
    // implicit-zero row init: np.argmax over {q(valid) or -1(invalid)} with
    // all uncomputed valid q == 0 -> max>=0, first index = first valid m.
    const float iv = (sNV > 0) ? 0.f : -1.0f;
    const int im = (sNV > 0) ? sFV : 0;
    #pragma unroll
    for (int i = 0; i < 4; ++i) { bv[i] = iv; bm[i] = im; }
  }
  #pragma unroll 2
  for (int j = 0; j < nc; ++j) {
    float4 t = sCBX[j];
    float ta = sCBA[j];
    int mm = sCBM[j];
    float lb = -1.0f; int li = 0;
    #pragma unroll
    for (int i = 0; i < 4; ++i) {
      float wx = fminf(ax2[i], t.z) - fmaxf(ax1[i], t.x);
      float wy = fminf(ay2[i], t.w) - fmaxf(ay1[i], t.y);
      float inter = fmaxf(wx, 0.f) * fmaxf(wy, 0.f);
      float uni = (sa[i] + ta) - inter;
      float q = inter * __builtin_amdgcn_rcpf(uni);
      if (q > bv[i]) { bv[i] = q; bm[i] = mm; }     // strict >: np first-max
      if (q > lb) { lb = q; li = i; }
    }
    float wmax = waveMax(lb);
    unsigned long long msk = __ballot(lb == wmax);
    int lead = __ffsll(msk) - 1;
    int wi = __builtin_amdgcn_readlane(li, lead);
    if (lane == 0) {
      int aw = base + wave * 64 + lead + wi * 512;   // sorted position
      sKey[mm][wave] = ((unsigned long long)__float_as_uint(wmax) << 32) |
                       (unsigned long long)(0x7FFFFFFFu - (unsigned)aw);
    }
  }

  // Phase C: losses (pre-override)
  double lL = 0.0, lC = 0.0;
  unsigned int npc = 0;
  #pragma unroll
  for (int i = 0; i < 4; ++i) {
    const int p = base + tid + i * 512;
    const size_t go = (size_t)b * A_N + aId[i];   // original-id gather
    bool conf = bv[i] >= OVTH;
    float2 cp = conf_pred[go];
    float mx = fmaxf(cp.x, cp.y), mn = fminf(cp.x, cp.y);
    float lse = mx + log1pf(expf(mn - mx));
    unsigned int bits = 0u;
    if (conf) {
      float ce = lse - cp.y;
      npc++; lC += (double)ce;
      float4 t = sTB[bm[i]];
      float4 an = sortedA[p];                       // exact original values
      float gx = ((t.x + t.z) * 0.5f - an.x) / (VAR0 * an.z);
      float gy = ((t.y + t.w) * 0.5f - an.y) / (VAR0 * an.w);
      float2 lp = loc_pred[go];
      lL += (double)(sl1(fabsf(lp.x - gx)) + sl1(fabsf(lp.y - gy)));
    } else {
      float ce = lse - cp.x;
      bits = __float_as_uint(ce);    // ce > 0 -> monotone, nonzero
      atomicAdd(&hh[bits >> 21], packCE(ce));
    }
    ceBits[(size_t)b * A_N + p] = bits;             // sorted order (order-free)
  }
  __syncthreads();

  // flushes
  for (int j = tid; j < 2048; j += 512) {
    unsigned long long v = hh[j];
    if (v) atomicAdd(&h1[(size_t)b * 2048 + j], v);
  }
  if (tid < M_N) {
    unsigned long long k0 = sKey[tid][0];
    #pragma unroll
    for (int w = 1; w < 8; ++w) {
      unsigned long long k2 = sKey[tid][w];
      k0 = (k2 > k0) ? k2 : k0;
    }
    if (k0) atomicMax(bpi + b * M_N + tid, k0);
  }
  for (int off = 32; off; off >>= 1) {
    lL += __shfl_down(lL, off);
    lC += __shfl_down(lC, off);
    npc += __shfl_down(npc, off);
  }
  if (lane == 0) { rL[wave] = lL; rC[wave] = lC; rN[wave] = npc; }
  __syncthreads();
  if (tid == 0) {
    double aL = 0, aC = 0; unsigned int n = 0;
    #pragma unroll
    for (int w = 0; w < 8; ++w) { aL += rL[w]; aC += rC[w]; n += rN[w]; }
    if (aL != 0.0) atomicAdd(lossL, aL);
    if (aC != 0.0) atomicAdd(lossCp, aC);
    if (n) atomicAdd(numpos + b, n);
  }
}

// ---------------------------------------------------------------- fixup pass
// 1 block, 512 threads = one per (b,m); wave w == batch w. Dedupe by sorted
// pos (max m wins = numpy last-write). Winner recomputes the anchor's match
// over ALL valid truths (identical op sequence; non-candidates give q=0 ->
// identical result to k_match), then patches the aggregates.
__launch_bounds__(512)
__global__ void k_fix(const float4* __restrict__ sortedA,
                      const unsigned int* __restrict__ sortedId,
                      const float*  __restrict__ targets,
                      const float2* __restrict__ loc_pred,
                      const float2* __restrict__ conf_pred,
                      unsigned long long* __restrict__ ws64,
                      unsigned int* __restrict__ ceBits)
{
  double* lossL  = (double*)(ws64 + 0);
  double* lossCp = (double*)(ws64 + 1);
  unsigned int* numpos = (unsigned int*)(ws64 + 2);
  const unsigned int* sortPos0 = (const unsigned int*)(ws64 + W_SP0);
  const unsigned long long* bpi = ws64 + W_BPI;
  unsigned long long* h1 = ws64 + W_H1;

  __shared__ int sP[512];
  __shared__ float4 sBXf[512];
  __shared__ float sAr[512];
  __shared__ unsigned char sVal[512];
  const int tid = threadIdx.x;
  const int b = tid >> 6, m = tid & 63;
  const float* t = targets + (size_t)tid * 5;
  float4 box = make_float4(t[0], t[1], t[2], t[3]);
  bool valid = t[4] > 0.f;
  unsigned long long vm = __ballot(valid);     // wave == batch
  int firstV = vm ? (__ffsll(vm) - 1) : 0;
  unsigned long long key = bpi[tid];
  int p = -1;
  if (valid) {
    unsigned int hi = (unsigned int)(key >> 32);
    p = (hi == 0u) ? (int)*sortPos0
                   : (int)(0x7FFFFFFFu - (unsigned)(key & 0xFFFFFFFFull));
  }
  sP[tid] = p;
  sBXf[tid] = box;
  sAr[tid] = (box.z - box.x) * (box.w - box.y);
  sVal[tid] = valid ? 1 : 0;
  __syncthreads();
  bool winner = (p >= 0);
  if (winner) {
    for (int m2 = m + 1; m2 < M_N; ++m2)
      if (sP[(b << 6) | m2] == p) { winner = false; break; }
  }
  if (winner) {
    float4 an = sortedA[p];
    unsigned int a = sortedId[p];
    const size_t go = (size_t)b * A_N + a;
    // recompute this anchor's pre-override match (exact same ops as k_match)
    float ax1 = an.x - an.z * 0.5f, ay1 = an.y - an.w * 0.5f;
    float ax2 = an.x + an.z * 0.5f, ay2 = an.y + an.w * 0.5f;
    float saA = (ax2 - ax1) * (ay2 - ay1);
    float bvv = 0.f; int bmm = firstV;
    for (int mm = 0; mm < M_N; ++mm) {
      if (sVal[(b << 6) | mm]) {
        float4 tb = sBXf[(b << 6) | mm];
        float ta = sAr[(b << 6) | mm];
        float wx = fminf(ax2, tb.z) - fmaxf(ax1, tb.x);
        float wy = fminf(ay2, tb.w) - fmaxf(ay1, tb.y);
        float inter = fmaxf(wx, 0.f) * fmaxf(wy, 0.f);
        float uni = (saA + ta) - inter;
        float q = inter * __builtin_amdgcn_rcpf(uni);
        if (q > bvv) { bvv = q; bmm = mm; }
      }
    }
    bool confOld = bvv >= OVTH;
    float2 cp = conf_pred[go];
    float mx = fmaxf(cp.x, cp.y), mn = fminf(cp.x, cp.y);
    float lse = mx + log1pf(expf(mn - mx));
    float2 lp = loc_pred[go];
    float gx = ((box.x + box.z) * 0.5f - an.x) / (VAR0 * an.z);
    float gy = ((box.y + box.w) * 0.5f - an.y) / (VAR0 * an.w);
    float newL = sl1(fabsf(lp.x - gx)) + sl1(fabsf(lp.y - gy));
    if (!confOld) {
      float ceN = lse - cp.x;
      unsigned int bits = __float_as_uint(ceN);
      atomicAdd(&h1[(size_t)b * 2048 + (bits >> 21)],
                (unsigned long long)(0ull - packCE(ceN)));
      ceBits[(size_t)b * A_N + p] = 0u;
      atomicAdd(lossCp, (double)(lse - cp.y));
      atomicAdd(&numpos[b], 1u);
      atomicAdd(lossL, (double)newL);
    } else {
      if (bmm != m) {
        float4 ob = sBXf[(b << 6) | bmm];
        float ox = ((ob.x + ob.z) * 0.5f - an.x) / (VAR0 * an.z);
        float oy = ((ob.y + ob.w) * 0.5f - an.y) / (VAR0 * an.w);
        float oldL = sl1(fabsf(lp.x - ox)) + sl1(fabsf(lp.y - oy));
        atomicAdd(lossL, (double)(newL - oldL));
      }
    }
  }
}

// ------------------------------------------------- radix-select helper (256t)
template <int PER>
__device__ void findBinP(const unsigned long long* __restrict__ h,
                         unsigned int k, unsigned int* scanBuf,
                         int* outT, unsigned int* outAb)
{
  const int tid = threadIdx.x;
  unsigned int c[PER];
  unsigned int ps = 0;
  #pragma unroll
  for (int j = 0; j < PER; ++j) {
    c[j] = (unsigned int)(h[tid * PER + j] >> CNT_SH);
    ps += c[j];
  }
  scanBuf[tid] = ps;
  __syncthreads();
  unsigned int v = ps;
  for (int off = 1; off < 256; off <<= 1) {
    unsigned int u = (tid + off < 256) ? scanBuf[tid + off] : 0u;
    __syncthreads();
    v += u;
    scanBuf[tid] = v;
    __syncthreads();
  }
  unsigned int above = v - ps;
  #pragma unroll
  for (int j = PER - 1; j >= 0; --j) {
    unsigned int cj = c[j];
    if (above < k && above + cj >= k) { *outT = tid * PER + j; *outAb = above; }
    above += cj;
  }
  __syncthreads();
}

// ----------------------------------------------------------- level-2 histogram
__launch_bounds__(256)
__global__ void k_sel2(const unsigned int* __restrict__ ceBits,
                       unsigned long long* __restrict__ ws64)
{
  const unsigned int* numpos = (const unsigned int*)(ws64 + 2);
  const unsigned long long* h1 = ws64 + W_H1;
  unsigned long long* h2 = ws64 + W_H2;
  __shared__ unsigned int scanBuf[256];
  __shared__ int sT; __shared__ unsigned int sAb;
  __shared__ unsigned long long hh[2048];
  const int b = blockIdx.y;
  const unsigned int P = numpos[b];
  const unsigned int k = min(3u * P, (unsigned)A_N - P);
  if (k == 0u) return;
  const int tid = threadIdx.x;
  findBinP<8>(h1 + (size_t)b * 2048, k, scanBuf, &sT, &sAb);
  const int t1 = sT;
  for (int j = tid; j < 2048; j += 256) hh[j] = 0ull;
  __syncthreads();
  const uint4* cb = (const uint4*)(ceBits + (size_t)b * A_N + blockIdx.x * 4096);
  for (int i = 0; i < 4; ++i) {
    uint4 v = cb[i * 256 + tid];
    unsigned int xs[4] = {v.x, v.y, v.z, v.w};
    #pragma unroll
    for (int c = 0; c < 4; ++c) {
      unsigned int x = xs[c];
      if (x && (int)(x >> 21) == t1)
        atomicAdd(&hh[(x >> 10) & 2047], packCE(__uint_as_float(x)));
    }
  }
  __syncthreads();
  for (int j = tid; j < 2048; j += 256) {
    unsigned long long v = hh[j];
    if (v) atomicAdd(&h2[(size_t)b * 2048 + j], v);
  }
}

// --------------------------------------------------------------- final combine
__launch_bounds__(256)
__global__ void k_final(unsigned long long* __restrict__ ws64,
                        float* __restrict__ out)
{
  const double* lossL  = (const double*)(ws64 + 0);
  const double* lossCp = (const double*)(ws64 + 1);
  const unsigned int* numpos = (const unsigned int*)(ws64 + 2);
  double* lossCn = (double*)(ws64 + 6);
  unsigned int* ticket = (unsigned int*)(ws64 + 7);
  const unsigned long long* h1 = ws64 + W_H1;
  const unsigned long long* h2 = ws64 + W_H2;
  __shared__ unsigned int scanBuf[256];
  __shared__ int sT; __shared__ unsigned int sAb;
  __shared__ double lred[4];
  const int b = blockIdx.x;
  const int tid = threadIdx.x;
  const unsigned int P = numpos[b];
  const unsigned int k = min(3u * P, (unsigned)A_N - P);
  if (k > 0u) {
    findBinP<8>(h1 + (size_t)b * 2048, k, scanBuf, &sT, &sAb);
    const int t1 = sT; const unsigned int k1 = k - sAb;
    findBinP<8>(h2 + (size_t)b * 2048, k1, scanBuf, &sT, &sAb);
    const int t2 = sT; const unsigned int k2 = k1 - sAb;
    double sfix = 0.0;
    for (int j = tid; j < 2048; j += 256) {
      if (j > t1) sfix += (double)(h1[(size_t)b * 2048 + j] & SUM_MASK);
      if (j > t2) sfix += (double)(h2[(size_t)b * 2048 + j] & SUM_MASK);
    }
    double s = sfix * INV_FIX;
    const int lane = tid & 63, wave = tid >> 6;
    for (int off = 32; off; off >>= 1) s += __shfl_down(s, off);
    if (lane == 0) lred[wave] = s;
    __syncthreads();
    if (tid == 0) {
      double tot = lred[0] + lred[1] + lred[2] + lred[3];
      tot += (double)k2 * (double)__uint_as_float(
                 (((unsigned)t1 << 21) | ((unsigned)t2 << 10)));
      atomicAdd(lossCn, tot);
    }
  }
  __threadfence();
  if (tid == 0) {
    unsigned int tk = atomicAdd(ticket, 1u);
    if (tk == B_N - 1) {
      double lcn = atomicAdd(lossCn, 0.0);
      double ll = *lossL, lcp = *lossCp;
      unsigned int tot = 0;
      #pragma unroll
      for (int i = 0; i < B_N; ++i) tot += numpos[i];
      double tn = (double)tot;
      out[0] = (float)(ll / tn);
      out[1] = (float)((lcp + lcn) / tn);
    }
  }
}

// -------------------------------------------------------------------- launcher
extern "C" void kernel_launch(void* const* d_in, const int* in_sizes, int n_in,
                              void* d_out, int out_size, void* d_ws, size_t ws_size,
                              hipStream_t stream)
{
  const float2* loc     = (const float2*)d_in[0];  // (B,A,2)
  const float2* confp   = (const float2*)d_in[1];  // (B,A,2)
  const float4* anchors = (const float4*)d_in[2];  // (A,4)
  const float*  targets = (const float*)d_in[3];   // (B,M,5)
  char* ws = (char*)d_ws;
  unsigned long long* ws64 = (unsigned long long*)d_ws;
  float4* sortedA = (float4*)(ws + ZBYTES);                      // 2 MB
  unsigned int* sortedId = (unsigned int*)(ws + ZBYTES + 2097152);   // 512 KB
  unsigned int* ceBits = (unsigned int*)(ws + ZBYTES + 2621440); // 4 MB

  (void)hipMemsetAsync(d_ws, 0, ZBYTES, stream);
  k_sort1<<<512, 256, 0, stream>>>(anchors, ws64);
  k_sort2<<<1, 64, 0, stream>>>(ws64);
  k_sort3<<<512, 256, 0, stream>>>(anchors, ws64, sortedA, sortedId);
  k_match<<<dim3(64, 8), 512, 0, stream>>>(sortedA, sortedId, targets, loc,
                                           confp, ws64, ceBits);
  k_fix<<<1, 512, 0, stream>>>(sortedA, sortedId, targets, loc, confp,
                               ws64, ceBits);
  k_sel2<<<dim3(32, 8), 256, 0, stream>>>(ceBits, ws64);
  k_final<<<8, 256, 0, stream>>>(ws64, (float*)d_out);
}